// Round 1
// baseline (6103.306 us; speedup 1.0000x reference)
//
#include <hip/hip_runtime.h>
#include <stdint.h>

typedef unsigned short u16;
typedef unsigned int u32;
typedef unsigned long long u64;
typedef __attribute__((ext_vector_type(8))) short short8;   // 8 x bf16
typedef __attribute__((ext_vector_type(4))) float f32x4;
typedef __attribute__((ext_vector_type(4))) int int4v;

#define SEQ 256
#define GATE_WGS 64
#define NWG 65          // 64 gate + 1 FE (d+y+feat fused)
#define A_ELE 49152     // elements per A ring slot (bf16): feat[16K] + h[32K]

__device__ __forceinline__ u16 f2bf(float f) {
  u32 u = __float_as_uint(f);
  u += 0x7FFFu + ((u >> 16) & 1u);
  return (u16)(u >> 16);
}
__device__ __forceinline__ short8 cvt8(const float* __restrict__ p) {
  short8 r;
#pragma unroll
  for (int j = 0; j < 8; ++j) r[j] = (short)f2bf(p[j]);
  return r;
}
__device__ __forceinline__ short8 cvt8v(const float* __restrict__ p) {  // 2x float4
  f32x4 a = *(const f32x4*)p, b = *(const f32x4*)(p + 4);
  short8 r;
#pragma unroll
  for (int j = 0; j < 4; ++j) { r[j] = (short)f2bf(a[j]); r[4 + j] = (short)f2bf(b[j]); }
  return r;
}
__device__ __forceinline__ float fast_tanh(float x) {
  return 1.0f - 2.0f / (1.0f + __expf(2.0f * x));
}
__device__ __forceinline__ float fast_sig(float x) {
  return 1.0f / (1.0f + __expf(-x));
}

union V16 { short8 s; u64 q[2]; };
// device-coherent 16B store (write through to agent coherence point)
__device__ __forceinline__ void stc16(u16* p, const u64* s) {
  __hip_atomic_store((u64*)p,     s[0], __ATOMIC_RELAXED, __HIP_MEMORY_SCOPE_AGENT);
  __hip_atomic_store((u64*)p + 1, s[1], __ATOMIC_RELAXED, __HIP_MEMORY_SCOPE_AGENT);
}
__device__ __forceinline__ void pollge(u32* p, u32 v) {
  while (__hip_atomic_load(p, __ATOMIC_RELAXED, __HIP_MEMORY_SCOPE_AGENT) < v) {}
}
__device__ __forceinline__ void setflag(u32* p, u32 v) {
  __hip_atomic_store(p, v, __ATOMIC_RELAXED, __HIP_MEMORY_SCOPE_AGENT);
}
// per-wave store drain: prior coherent stores reach coherence point before flag
#define VMCNT0() asm volatile("s_waitcnt vmcnt(0)" ::: "memory")
// consumer-side: invalidate L1/L2 so plain loads see agent-coherent data
#define ACQ_FENCE() __builtin_amdgcn_fence(__ATOMIC_ACQUIRE, "agent")

// ---------------------------------------------------------------------------
// Prep: feat_0 -> Abuf slot0 feat section; zero slot0 h section; zero flags;
// pack W_hx (bf16) into MFMA B-fragment order for the FE WG.
// A-frag chunk layout: chunk = (kb*4 + mt)*64 + lane; lane holds
// A[m = mt*16 + (lane&15)][k = kb*32 + (lane>>4)*8 + j], j=0..7.
// ---------------------------------------------------------------------------
__global__ void prep_kernel(const float* __restrict__ x, const float* __restrict__ W_fx,
                            const float* __restrict__ b_fx, const float* __restrict__ W_hx,
                            u16* __restrict__ Abuf0, u16* __restrict__ Whx_pack,
                            u32* __restrict__ flags) {
  int b = blockIdx.x, tid = threadIdx.x;
  if (b < 64) {
    int gidx = b * 256 + tid;          // 16384 elements of feat_0 [64][256]
    int chunk = gidx >> 3, j = gidx & 7;
    int kb = chunk >> 8, mt = (chunk >> 6) & 3, l = chunk & 63;
    int m = mt * 16 + (l & 15);
    int c = kb * 32 + (l >> 4) * 8 + j;
    float s = b_fx[c];
    const float* xr = x + m * 64;      // t = 0
    const float* wr = W_fx + c * 64;
    for (int k = 0; k < 64; ++k) s += xr[k] * wr[k];
    Abuf0[chunk * 8 + j] = f2bf(fast_tanh(s));
  } else if (b == 64) {
    for (int it = 0; it < 16; ++it) {  // zero h-section of slot0: chunks 2048..6143
      int chunk = it * 256 + tid;
      *(int4v*)(Abuf0 + (2048 + chunk) * 8) = (int4v){0, 0, 0, 0};
    }
    for (int k = 0; k < 5; ++k) {
      int i = k * 256 + tid;
      if (i < 1168) flags[i] = 0u;
    }
  } else {
    // W_hx pack: 16384 chunks of 16B; blocks 65..72, 2048 chunks each.
    // chunk cid: kb = cid>>10, nt16 = (cid>>6)&15, ln = cid&63
    //   value = W_hx[row = nt16*16+(ln&15)][k = kb*32+(ln>>4)*8 .. +8) as bf16
    int base = (b - 65) * 2048;
#pragma unroll
    for (int it = 0; it < 8; ++it) {
      int cid = base + it * 256 + tid;
      int kb = cid >> 10, rem = cid & 1023, nt16 = rem >> 6, l = rem & 63;
      int row = nt16 * 16 + (l & 15);
      int k = kb * 32 + ((l >> 4) << 3);
      *(short8*)(Whx_pack + cid * 8) = cvt8v(W_hx + row * 512 + k);
    }
  }
}

// ---------------------------------------------------------------------------
// Persistent recurrent kernel. 65 WGs x 256 threads. Fence-free data publish:
//   hflag[wg] = t+1 after gate wg stored h_{t+1} ; consumers poll >= t for h_t
//   fc        = t+1 after FE stored feat_{t+1}   ; gates poll >= t for feat_t
// Consumers: poll flag -> __syncthreads -> agent-acquire fence -> PLAIN loads.
// ---------------------------------------------------------------------------
__global__ void __launch_bounds__(256, 1)
rnn_kernel(const float* __restrict__ x, const float* __restrict__ msel,
           const float* __restrict__ W_fx, const float* __restrict__ b_fx,
           const float* __restrict__ W_ih, const float* __restrict__ W_hh,
           const float* __restrict__ b_ih, const float* __restrict__ b_hh,
           const float* __restrict__ W_hx, const float* __restrict__ b_hx,
           const float* __restrict__ W_out, const float* __restrict__ b_out,
           float* __restrict__ out,
           u16* __restrict__ Abase, const u16* __restrict__ Whx_pack,
           u32* __restrict__ flags) {
  __shared__ __attribute__((aligned(16))) char smem[143360];
  const int wgid = blockIdx.x;
  const int tid = threadIdx.x;
  const int wv = tid >> 6, ln = tid & 63;
  u32* hflag = flags;          // stride 16 u32 (64B lines)
  u32* fcv   = flags + 1152;

  if (wgid < GATE_WGS) {
    // ===== gate WG: 8 hidden units -> 32 gate cols; B-frags in REGISTERS =====
    // Split-phase: W_hh part (needs h_t) first, then poll feat_t and W_ih part.
    const int wg = wgid;
    float* red = (float*)smem;                 // [4 wv][8 tile][64][4] = 32KB
    u16* hstage = (u16*)(smem + 32768);        // [4 mt][16 m15][8 u] = 1KB
    short8 BregH[4][2];   // h part: kb_global = 8 + wv*4 + kk
#pragma unroll
    for (int kk = 0; kk < 4; ++kk)
#pragma unroll
      for (int nt = 0; nt < 2; ++nt) {
        int n = ln & 15;
        int gate = nt * 2 + (n >> 3), unit = n & 7;
        int row = gate * 512 + wg * 8 + unit;
        BregH[kk][nt] = cvt8(W_hh + row * 512 + (wv * 4 + kk) * 32 + (ln >> 4) * 8);
      }
    short8 BregF[2][2];   // feat part: kb_global = wv*2 + kk
#pragma unroll
    for (int kk = 0; kk < 2; ++kk)
#pragma unroll
      for (int nt = 0; nt < 2; ++nt) {
        int n = ln & 15;
        int gate = nt * 2 + (n >> 3), unit = n & 7;
        int row = gate * 512 + wg * 8 + unit;
        BregF[kk][nt] = cvt8(W_ih + row * 256 + (wv * 2 + kk) * 32 + (ln >> 4) * 8);
      }
    float bsum_r[2][4];
#pragma unroll
    for (int it = 0; it < 2; ++it) {
      int u = (it * 256 + tid) & 7;
#pragma unroll
      for (int g = 0; g < 4; ++g) {
        int row = g * 512 + wg * 8 + u;
        bsum_r[it][g] = b_ih[row] + b_hh[row];
      }
    }
    float creg[2] = {0.f, 0.f};
    const int kbW = 8 + (wg >> 2), qW = wg & 3;   // this WG's h region
    int r = 0, rn = 1;
    for (int t = 0; t < SEQ; ++t) {
      if (tid < 64) pollge(&hflag[tid * 16], (u32)t);
      __syncthreads();
      ACQ_FENCE();
      const u16* A = Abase + r * A_ELE;
      u16* An = Abase + rn * A_ELE;
      f32x4 acc[2][4];
#pragma unroll
      for (int nt = 0; nt < 2; nt++)
#pragma unroll
        for (int mt = 0; mt < 4; mt++) acc[nt][mt] = (f32x4){0.f, 0.f, 0.f, 0.f};
      // --- phase 1: h part (plain loads, post-fence) ---
      short8 ah[4][4];
#pragma unroll
      for (int kk = 0; kk < 4; ++kk)
#pragma unroll
        for (int mt = 0; mt < 4; ++mt)
          ah[kk][mt] = *(const short8*)(A + (((8 + wv * 4 + kk) * 4 + mt) * 64 + ln) * 8);
#pragma unroll
      for (int kk = 0; kk < 4; ++kk)
#pragma unroll
        for (int nt = 0; nt < 2; nt++)
#pragma unroll
          for (int mt = 0; mt < 4; mt++)
            acc[nt][mt] = __builtin_amdgcn_mfma_f32_16x16x32_bf16(ah[kk][mt], BregH[kk][nt], acc[nt][mt], 0, 0, 0);
      // --- phase 2: feat part (poll feat only after h compute) ---
      if (tid == 64) pollge(fcv, (u32)t);
      __syncthreads();
      ACQ_FENCE();
      short8 af[2][4];
#pragma unroll
      for (int kk = 0; kk < 2; ++kk)
#pragma unroll
        for (int mt = 0; mt < 4; ++mt)
          af[kk][mt] = *(const short8*)(A + (((wv * 2 + kk) * 4 + mt) * 64 + ln) * 8);
#pragma unroll
      for (int kk = 0; kk < 2; ++kk)
#pragma unroll
        for (int nt = 0; nt < 2; nt++)
#pragma unroll
          for (int mt = 0; mt < 4; mt++)
            acc[nt][mt] = __builtin_amdgcn_mfma_f32_16x16x32_bf16(af[kk][mt], BregF[kk][nt], acc[nt][mt], 0, 0, 0);
      // one-shot 4-wave reduction staging
#pragma unroll
      for (int nt = 0; nt < 2; nt++)
#pragma unroll
        for (int mt = 0; mt < 4; mt++)
          *(f32x4*)(red + ((wv * 8 + nt * 4 + mt) * 64 + ln) * 4) = acc[nt][mt];
      __syncthreads();
      // LSTM cell: 512 (m,u) items, 2/thread; sum 4 wave-partials inline
#pragma unroll
      for (int it = 0; it < 2; ++it) {
        int item = it * 256 + tid;
        int m = item >> 3, u = item & 7;
        int mt = m >> 4, lq = ((m & 15) >> 2) * 16, reg = m & 3;
        float g4[4];
#pragma unroll
        for (int g = 0; g < 4; ++g) {
          float s = bsum_r[it][g];
          int base = ((g >> 1) * 4 + mt) * 64 + lq + (g & 1) * 8 + u;
#pragma unroll
          for (int w = 0; w < 4; ++w) s += red[(w * 8 * 64 + base) * 4 + reg];
          g4[g] = s;
        }
        float ii = fast_sig(g4[0]), ff = fast_sig(g4[1]);
        float gg = fast_tanh(g4[2]), oo = fast_sig(g4[3]);
        float cn = ff * creg[it] + ii * gg;
        creg[it] = cn;
        float h = oo * fast_tanh(cn);
        hstage[(mt * 16 + (m & 15)) * 8 + u] = f2bf(h);
      }
      __syncthreads();
      if (tid < 64) {   // 16B coherent stores of this WG's 1KB h region
        int mt2 = tid >> 4, m15 = tid & 15;
        u16* dst = An + (((kbW * 4 + mt2) * 64 + qW * 16 + m15) * 8);
        stc16(dst, (const u64*)(hstage + tid * 8));
        VMCNT0();
      }
      __syncthreads();
      if (tid == 0) setflag(&hflag[wg * 16], (u32)(t + 1));
      r = rn; rn = (rn == 2) ? 0 : rn + 1;
    }
  } else {
    // ===== FE WG: d = tanh(h@Whx^T+b); y = d@Wout^T+b; feat_{t+1} blend =====
    // Single WG, all handoffs through LDS: removes the d->y coherent hop.
    u16* hlds   = (u16*)smem;                  // 64KB: copy of ring h section
    u16* dlds   = (u16*)(smem + 65536);        // [64 m][264] bf16 (pad vs banks)
    u16* ystage = (u16*)(smem + 99328);        // [64][80]
    u16* fstage = (u16*)(smem + 109568);       // [64][264]
    const int c15 = ln & 15, qq = ln >> 4;
    short8 Breg2[8];   // W_out rows (this wave's 16 out cols), K=256
#pragma unroll
    for (int kb = 0; kb < 8; ++kb)
      Breg2[kb] = cvt8(W_out + (wv * 16 + c15) * 256 + kb * 32 + qq * 8);
    short8 WfR[2][4];  // W_fx rows (this wave's 64 feat cols), K=64
#pragma unroll
    for (int kk = 0; kk < 2; ++kk)
#pragma unroll
      for (int nt = 0; nt < 4; ++nt)
        WfR[kk][nt] = cvt8(W_fx + ((wv * 4 + nt) * 16 + c15) * 64 + kk * 32 + qq * 8);
    float bout_r = b_out[wv * 16 + c15];
    float bfx_r[4];
#pragma unroll
    for (int nt = 0; nt < 4; ++nt) bfx_r[nt] = b_fx[(wv * 4 + nt) * 16 + c15];
    float bhx_r[4];
#pragma unroll
    for (int nt = 0; nt < 4; ++nt) bhx_r[nt] = b_hx[wv * 64 + nt * 16 + c15];

    int r = 0, rn = 1;
    for (int t = 0; t < SEQ; ++t) {
      // prefetch x[t+1] + msel[t+1] before the poll (plain cached loads)
      short8 xa[2][4];
      float mix = 0.f;
      if (t < SEQ - 1) {
        mix = msel[t + 1];
#pragma unroll
        for (int kb = 0; kb < 2; ++kb)
#pragma unroll
          for (int mt = 0; mt < 4; ++mt)
            xa[kb][mt] = cvt8v(x + ((t + 1) * 64 + mt * 16 + c15) * 64 + kb * 32 + qq * 8);
      }
      if (tid < 64) pollge(&hflag[tid * 16], (u32)t);
      __syncthreads();
      ACQ_FENCE();
      const u16* A = Abase + r * A_ELE;
      u16* An = Abase + rn * A_ELE;
      // copy h section (chunks 2048..6143 = 64KB) -> LDS, frag layout preserved
#pragma unroll
      for (int it = 0; it < 16; ++it) {
        int idx = it * 256 + tid;
        *(short8*)(hlds + idx * 8) = *(const short8*)(A + (2048 + idx) * 8);
      }
      __syncthreads();
      // GEMM1: d_pre = h @ W_hx^T ; wave wv owns dec cols [wv*64, wv*64+64)
      // full K=512 per wave (no cross-wave reduce); B streamed from L2 pack
      f32x4 acc1[4][4];
#pragma unroll
      for (int nt = 0; nt < 4; nt++)
#pragma unroll
        for (int mt = 0; mt < 4; mt++) acc1[nt][mt] = (f32x4){0.f, 0.f, 0.f, 0.f};
#pragma unroll 4
      for (int kb = 0; kb < 16; ++kb) {
        short8 ahf[4];
#pragma unroll
        for (int mt = 0; mt < 4; ++mt)
          ahf[mt] = *(const short8*)(hlds + ((kb * 4 + mt) * 64 + ln) * 8);
        short8 bw[4];
#pragma unroll
        for (int nt = 0; nt < 4; ++nt)
          bw[nt] = *(const short8*)(Whx_pack + ((kb * 16 + wv * 4 + nt) * 64 + ln) * 8);
#pragma unroll
        for (int nt = 0; nt < 4; ++nt)
#pragma unroll
          for (int mt = 0; mt < 4; ++mt)
            acc1[nt][mt] = __builtin_amdgcn_mfma_f32_16x16x32_bf16(ahf[mt], bw[nt], acc1[nt][mt], 0, 0, 0);
      }
      // tanh -> dlds[m][dec], pitch 264 (bank spread for frag re-reads)
#pragma unroll
      for (int nt = 0; nt < 4; ++nt)
#pragma unroll
        for (int mt = 0; mt < 4; ++mt)
#pragma unroll
          for (int r2 = 0; r2 < 4; ++r2) {
            int m = mt * 16 + qq * 4 + r2;
            int n = wv * 64 + nt * 16 + c15;
            dlds[m * 264 + n] = f2bf(fast_tanh(acc1[nt][mt][r2] + bhx_r[nt]));
          }
      __syncthreads();
      // GEMM2: y = d @ W_out^T ; wave wv owns out cols [wv*16, wv*16+16), full K=256
      f32x4 acc2[4];
#pragma unroll
      for (int mt = 0; mt < 4; mt++) acc2[mt] = (f32x4){0.f, 0.f, 0.f, 0.f};
#pragma unroll
      for (int kb = 0; kb < 8; ++kb) {
        short8 a2[4];
#pragma unroll
        for (int mt = 0; mt < 4; ++mt)
          a2[mt] = *(const short8*)(dlds + (mt * 16 + c15) * 264 + kb * 32 + qq * 8);
#pragma unroll
        for (int mt = 0; mt < 4; ++mt)
          acc2[mt] = __builtin_amdgcn_mfma_f32_16x16x32_bf16(a2[mt], Breg2[kb], acc2[mt], 0, 0, 0);
      }
#pragma unroll
      for (int mt = 0; mt < 4; ++mt)
#pragma unroll
        for (int r2 = 0; r2 < 4; ++r2) {
          float yv = acc2[mt][r2] + bout_r;
          int row = mt * 16 + qq * 4 + r2;
          out[t * 4096 + row * 64 + wv * 16 + c15] = yv;   // f32 output (plain)
          ystage[row * 80 + wv * 16 + c15] = f2bf(yv);
        }
      __syncthreads();
      if (t < SEQ - 1) {
        f32x4 au[4][4], tf[4][4];
#pragma unroll
        for (int nt = 0; nt < 4; nt++)
#pragma unroll
          for (int mt = 0; mt < 4; mt++) {
            au[nt][mt] = (f32x4){0.f, 0.f, 0.f, 0.f};
            tf[nt][mt] = (f32x4){0.f, 0.f, 0.f, 0.f};
          }
#pragma unroll
        for (int kb = 0; kb < 2; ++kb) {
          int koff = kb * 32 + qq * 8;
          short8 ya[4];
#pragma unroll
          for (int mt = 0; mt < 4; mt++)
            ya[mt] = *(const short8*)(ystage + (mt * 16 + c15) * 80 + koff);
#pragma unroll
          for (int nt = 0; nt < 4; nt++)
#pragma unroll
            for (int mt = 0; mt < 4; mt++) {
              au[nt][mt] = __builtin_amdgcn_mfma_f32_16x16x32_bf16(ya[mt], WfR[kb][nt], au[nt][mt], 0, 0, 0);
              tf[nt][mt] = __builtin_amdgcn_mfma_f32_16x16x32_bf16(xa[kb][mt], WfR[kb][nt], tf[nt][mt], 0, 0, 0);
            }
        }
#pragma unroll
        for (int nt = 0; nt < 4; nt++)
#pragma unroll
          for (int mt = 0; mt < 4; mt++)
#pragma unroll
            for (int r2 = 0; r2 < 4; r2++) {
              float f = mix * fast_tanh(au[nt][mt][r2] + bfx_r[nt]) +
                        (1.f - mix) * fast_tanh(tf[nt][mt][r2] + bfx_r[nt]);
              int row = mt * 16 + qq * 4 + r2;
              fstage[row * 264 + (wv * 4 + nt) * 16 + c15] = f2bf(f);
            }
        __syncthreads();
#pragma unroll
        for (int it = 0; it < 8; ++it) {       // fstage -> An feat section, coherent
          int chunk = it * 256 + tid;
          int kb = chunk >> 8, l = chunk & 63;
          int m = ((chunk >> 6) & 3) * 16 + (l & 15);
          int k = kb * 32 + (l >> 4) * 8;
          V16 v; v.s = *(const short8*)(fstage + m * 264 + k);
          stc16(An + chunk * 8, v.q);
        }
        VMCNT0();
        __syncthreads();
        if (tid == 0) setflag(fcv, (u32)(t + 1));
      }
      r = rn; rn = (rn == 2) ? 0 : rn + 1;
    }
  }
}

extern "C" void kernel_launch(void* const* d_in, const int* in_sizes, int n_in,
                              void* d_out, int out_size, void* d_ws, size_t ws_size,
                              hipStream_t stream) {
  const float* x     = (const float*)d_in[0];
  const float* msel  = (const float*)d_in[1];
  const float* W_fx  = (const float*)d_in[2];
  const float* b_fx  = (const float*)d_in[3];
  const float* W_ih  = (const float*)d_in[4];
  const float* W_hh  = (const float*)d_in[5];
  const float* b_ih  = (const float*)d_in[6];
  const float* b_hh  = (const float*)d_in[7];
  const float* W_hx  = (const float*)d_in[8];
  const float* b_hx  = (const float*)d_in[9];
  const float* W_out = (const float*)d_in[10];
  const float* b_out = (const float*)d_in[11];

  uint8_t* ws = (uint8_t*)d_ws;
  u16* Abase    = (u16*)ws;                 // ring of 3 x 98304 B
  u16* Whx_pack = (u16*)(ws + 294912);      // 262144 B (bf16 frag-packed W_hx)
  u32* flags    = (u32*)(ws + 557056);      // 4672 B

  prep_kernel<<<73, 256, 0, stream>>>(x, W_fx, b_fx, W_hx, Abase, Whx_pack, flags);
  rnn_kernel<<<NWG, 256, 0, stream>>>(x, msel, W_fx, b_fx, W_ih, W_hh, b_ih, b_hh,
                                      W_hx, b_hx, W_out, b_out,
                                      (float*)d_out, Abase, Whx_pack, flags);
}

// Round 2
// 5831.831 us; speedup vs baseline: 1.0466x; 1.0466x over previous
//
#include <hip/hip_runtime.h>
#include <stdint.h>

typedef unsigned short u16;
typedef unsigned int u32;
typedef unsigned long long u64;
typedef __attribute__((ext_vector_type(8))) short short8;   // 8 x bf16
typedef __attribute__((ext_vector_type(4))) float f32x4;
typedef __attribute__((ext_vector_type(4))) int int4v;

#define SEQ 256
#define GATE_WGS 64
#define NWG 65          // 64 gate + 1 FE (d+y+feat fused)
#define A_ELE 49152     // elements per A ring slot (bf16): feat[16K] + h[32K]

__device__ __forceinline__ u16 f2bf(float f) {
  u32 u = __float_as_uint(f);
  u += 0x7FFFu + ((u >> 16) & 1u);
  return (u16)(u >> 16);
}
__device__ __forceinline__ short8 cvt8(const float* __restrict__ p) {
  short8 r;
#pragma unroll
  for (int j = 0; j < 8; ++j) r[j] = (short)f2bf(p[j]);
  return r;
}
__device__ __forceinline__ short8 cvt8v(const float* __restrict__ p) {  // 2x float4
  f32x4 a = *(const f32x4*)p, b = *(const f32x4*)(p + 4);
  short8 r;
#pragma unroll
  for (int j = 0; j < 4; ++j) { r[j] = (short)f2bf(a[j]); r[4 + j] = (short)f2bf(b[j]); }
  return r;
}
__device__ __forceinline__ float fast_tanh(float x) {
  return 1.0f - 2.0f / (1.0f + __expf(2.0f * x));
}
__device__ __forceinline__ float fast_sig(float x) {
  return 1.0f / (1.0f + __expf(-x));
}

union V16 { short8 s; u64 q[2]; };
// device-coherent 16B load/store (bypass L1/L2 -> coherence point), fence-free
__device__ __forceinline__ short8 ldc16(const u16* p) {
  V16 v;
  v.q[0] = __hip_atomic_load((const u64*)p,     __ATOMIC_RELAXED, __HIP_MEMORY_SCOPE_AGENT);
  v.q[1] = __hip_atomic_load((const u64*)p + 1, __ATOMIC_RELAXED, __HIP_MEMORY_SCOPE_AGENT);
  return v.s;
}
__device__ __forceinline__ void stc16(u16* p, const u64* s) {
  __hip_atomic_store((u64*)p,     s[0], __ATOMIC_RELAXED, __HIP_MEMORY_SCOPE_AGENT);
  __hip_atomic_store((u64*)p + 1, s[1], __ATOMIC_RELAXED, __HIP_MEMORY_SCOPE_AGENT);
}
__device__ __forceinline__ void pollge(u32* p, u32 v) {
  while (__hip_atomic_load(p, __ATOMIC_RELAXED, __HIP_MEMORY_SCOPE_AGENT) < v) {}
}
__device__ __forceinline__ void setflag(u32* p, u32 v) {
  __hip_atomic_store(p, v, __ATOMIC_RELAXED, __HIP_MEMORY_SCOPE_AGENT);
}
// per-wave store drain: prior coherent stores reach coherence point before flag
#define VMCNT0() asm volatile("s_waitcnt vmcnt(0)" ::: "memory")

// ---------------------------------------------------------------------------
// Prep: feat_0 -> Abuf slot0 feat section; zero slot0 h section; zero flags;
// pack W_hx (bf16) into MFMA B-fragment order for the FE WG.
// A-frag chunk layout: chunk = (kb*4 + mt)*64 + lane; lane holds
// A[m = mt*16 + (lane&15)][k = kb*32 + (lane>>4)*8 + j], j=0..7.
// ---------------------------------------------------------------------------
__global__ void prep_kernel(const float* __restrict__ x, const float* __restrict__ W_fx,
                            const float* __restrict__ b_fx, const float* __restrict__ W_hx,
                            u16* __restrict__ Abuf0, u16* __restrict__ Whx_pack,
                            u32* __restrict__ flags) {
  int b = blockIdx.x, tid = threadIdx.x;
  if (b < 64) {
    int gidx = b * 256 + tid;          // 16384 elements of feat_0 [64][256]
    int chunk = gidx >> 3, j = gidx & 7;
    int kb = chunk >> 8, mt = (chunk >> 6) & 3, l = chunk & 63;
    int m = mt * 16 + (l & 15);
    int c = kb * 32 + (l >> 4) * 8 + j;
    float s = b_fx[c];
    const float* xr = x + m * 64;      // t = 0
    const float* wr = W_fx + c * 64;
    for (int k = 0; k < 64; ++k) s += xr[k] * wr[k];
    Abuf0[chunk * 8 + j] = f2bf(fast_tanh(s));
  } else if (b == 64) {
    for (int it = 0; it < 16; ++it) {  // zero h-section of slot0: chunks 2048..6143
      int chunk = it * 256 + tid;
      *(int4v*)(Abuf0 + (2048 + chunk) * 8) = (int4v){0, 0, 0, 0};
    }
    for (int k = 0; k < 5; ++k) {
      int i = k * 256 + tid;
      if (i < 1168) flags[i] = 0u;
    }
  } else {
    // W_hx pack: 16384 chunks of 16B; blocks 65..72, 2048 chunks each.
    // chunk cid: kb = cid>>10, nt16 = (cid>>6)&15, ln = cid&63
    //   value = W_hx[row = nt16*16+(ln&15)][k = kb*32+(ln>>4)*8 .. +8) as bf16
    int base = (b - 65) * 2048;
#pragma unroll
    for (int it = 0; it < 8; ++it) {
      int cid = base + it * 256 + tid;
      int kb = cid >> 10, rem = cid & 1023, nt16 = rem >> 6, l = rem & 63;
      int row = nt16 * 16 + (l & 15);
      int k = kb * 32 + ((l >> 4) << 3);
      *(short8*)(Whx_pack + cid * 8) = cvt8v(W_hx + row * 512 + k);
    }
  }
}

// ---------------------------------------------------------------------------
// Persistent recurrent kernel. 65 WGs x 256 threads. Fence-free coherent flow:
//   hflag[wg] = t+1 after gate wg stored h_{t+1} ; consumers poll >= t for h_t
//   fc        = t+1 after FE stored feat_{t+1}   ; gates poll >= t for feat_t
// All cross-WG data moves via ldc16/stc16 (relaxed agent atomics) — NO fences.
// ---------------------------------------------------------------------------
__global__ void __launch_bounds__(256, 1)
rnn_kernel(const float* __restrict__ x, const float* __restrict__ msel,
           const float* __restrict__ W_fx, const float* __restrict__ b_fx,
           const float* __restrict__ W_ih, const float* __restrict__ W_hh,
           const float* __restrict__ b_ih, const float* __restrict__ b_hh,
           const float* __restrict__ W_hx, const float* __restrict__ b_hx,
           const float* __restrict__ W_out, const float* __restrict__ b_out,
           float* __restrict__ out,
           u16* __restrict__ Abase, const u16* __restrict__ Whx_pack,
           u32* __restrict__ flags) {
  __shared__ __attribute__((aligned(16))) char smem[143360];
  const int wgid = blockIdx.x;
  const int tid = threadIdx.x;
  const int wv = tid >> 6, ln = tid & 63;
  u32* hflag = flags;          // stride 16 u32 (64B lines)
  u32* fcv   = flags + 1152;

  if (wgid < GATE_WGS) {
    // ===== gate WG: 8 hidden units -> 32 gate cols; B-frags in REGISTERS =====
    // Split-phase: W_hh part (needs h_t) first; poll feat_t only after h MFMAs
    // (feat_t arrives later than h_t: it sits at the end of the FE chain).
    const int wg = wgid;
    float* red = (float*)smem;                 // [4 wv][8 tile][64][4] = 32KB
    u16* hstage = (u16*)(smem + 32768);        // [4 mt][16 m15][8 u] = 1KB
    short8 BregH[4][2];   // h part: kb_global = 8 + wv*4 + kk
#pragma unroll
    for (int kk = 0; kk < 4; ++kk)
#pragma unroll
      for (int nt = 0; nt < 2; ++nt) {
        int n = ln & 15;
        int gate = nt * 2 + (n >> 3), unit = n & 7;
        int row = gate * 512 + wg * 8 + unit;
        BregH[kk][nt] = cvt8(W_hh + row * 512 + (wv * 4 + kk) * 32 + (ln >> 4) * 8);
      }
    short8 BregF[2][2];   // feat part: kb_global = wv*2 + kk
#pragma unroll
    for (int kk = 0; kk < 2; ++kk)
#pragma unroll
      for (int nt = 0; nt < 2; ++nt) {
        int n = ln & 15;
        int gate = nt * 2 + (n >> 3), unit = n & 7;
        int row = gate * 512 + wg * 8 + unit;
        BregF[kk][nt] = cvt8(W_ih + row * 256 + (wv * 2 + kk) * 32 + (ln >> 4) * 8);
      }
    float bsum_r[2][4];
#pragma unroll
    for (int it = 0; it < 2; ++it) {
      int u = (it * 256 + tid) & 7;
#pragma unroll
      for (int g = 0; g < 4; ++g) {
        int row = g * 512 + wg * 8 + u;
        bsum_r[it][g] = b_ih[row] + b_hh[row];
      }
    }
    float creg[2] = {0.f, 0.f};
    const int kbW = 8 + (wg >> 2), qW = wg & 3;   // this WG's h region
    int r = 0, rn = 1;
    for (int t = 0; t < SEQ; ++t) {
      if (tid < 64) pollge(&hflag[tid * 16], (u32)t);
      __syncthreads();
      const u16* A = Abase + r * A_ELE;
      u16* An = Abase + rn * A_ELE;
      f32x4 acc[2][4];
#pragma unroll
      for (int nt = 0; nt < 2; nt++)
#pragma unroll
        for (int mt = 0; mt < 4; mt++) acc[nt][mt] = (f32x4){0.f, 0.f, 0.f, 0.f};
      // --- phase 1: h part (coherent frag loads) ---
      short8 ah[4][4];
#pragma unroll
      for (int kk = 0; kk < 4; ++kk)
#pragma unroll
        for (int mt = 0; mt < 4; ++mt)
          ah[kk][mt] = ldc16(A + (((8 + wv * 4 + kk) * 4 + mt) * 64 + ln) * 8);
#pragma unroll
      for (int kk = 0; kk < 4; ++kk)
#pragma unroll
        for (int nt = 0; nt < 2; nt++)
#pragma unroll
          for (int mt = 0; mt < 4; mt++)
            acc[nt][mt] = __builtin_amdgcn_mfma_f32_16x16x32_bf16(ah[kk][mt], BregH[kk][nt], acc[nt][mt], 0, 0, 0);
      // --- phase 2: feat part (poll feat only after h compute) ---
      if (tid == 64) pollge(fcv, (u32)t);
      __syncthreads();
      short8 af[2][4];
#pragma unroll
      for (int kk = 0; kk < 2; ++kk)
#pragma unroll
        for (int mt = 0; mt < 4; ++mt)
          af[kk][mt] = ldc16(A + (((wv * 2 + kk) * 4 + mt) * 64 + ln) * 8);
#pragma unroll
      for (int kk = 0; kk < 2; ++kk)
#pragma unroll
        for (int nt = 0; nt < 2; nt++)
#pragma unroll
          for (int mt = 0; mt < 4; mt++)
            acc[nt][mt] = __builtin_amdgcn_mfma_f32_16x16x32_bf16(af[kk][mt], BregF[kk][nt], acc[nt][mt], 0, 0, 0);
      // one-shot 4-wave reduction staging
#pragma unroll
      for (int nt = 0; nt < 2; nt++)
#pragma unroll
        for (int mt = 0; mt < 4; mt++)
          *(f32x4*)(red + ((wv * 8 + nt * 4 + mt) * 64 + ln) * 4) = acc[nt][mt];
      __syncthreads();
      // LSTM cell: 512 (m,u) items, 2/thread; sum 4 wave-partials inline
#pragma unroll
      for (int it = 0; it < 2; ++it) {
        int item = it * 256 + tid;
        int m = item >> 3, u = item & 7;
        int mt = m >> 4, lq = ((m & 15) >> 2) * 16, reg = m & 3;
        float g4[4];
#pragma unroll
        for (int g = 0; g < 4; ++g) {
          float s = bsum_r[it][g];
          int base = ((g >> 1) * 4 + mt) * 64 + lq + (g & 1) * 8 + u;
#pragma unroll
          for (int w = 0; w < 4; ++w) s += red[(w * 8 * 64 + base) * 4 + reg];
          g4[g] = s;
        }
        float ii = fast_sig(g4[0]), ff = fast_sig(g4[1]);
        float gg = fast_tanh(g4[2]), oo = fast_sig(g4[3]);
        float cn = ff * creg[it] + ii * gg;
        creg[it] = cn;
        float h = oo * fast_tanh(cn);
        hstage[(mt * 16 + (m & 15)) * 8 + u] = f2bf(h);
      }
      __syncthreads();
      if (tid < 64) {   // 16B coherent stores of this WG's 1KB h region
        int mt2 = tid >> 4, m15 = tid & 15;
        u16* dst = An + (((kbW * 4 + mt2) * 64 + qW * 16 + m15) * 8);
        stc16(dst, (const u64*)(hstage + tid * 8));
        VMCNT0();
      }
      __syncthreads();
      if (tid == 0) setflag(&hflag[wg * 16], (u32)(t + 1));
      r = rn; rn = (rn == 2) ? 0 : rn + 1;
    }
  } else {
    // ===== FE WG: d = tanh(h@Whx^T+b); y = d@Wout^T+b; feat_{t+1} blend =====
    // Single WG, all handoffs through LDS: removes the d->y coherent hop.
    u16* hlds   = (u16*)smem;                  // 64KB: copy of ring h section
    u16* dlds   = (u16*)(smem + 65536);        // [64 m][264] bf16 (pad vs banks)
    u16* ystage = (u16*)(smem + 99328);        // [64][80]
    u16* fstage = (u16*)(smem + 109568);       // [64][264]
    const int c15 = ln & 15, qq = ln >> 4;
    short8 Breg2[8];   // W_out rows (this wave's 16 out cols), K=256
#pragma unroll
    for (int kb = 0; kb < 8; ++kb)
      Breg2[kb] = cvt8(W_out + (wv * 16 + c15) * 256 + kb * 32 + qq * 8);
    short8 WfR[2][4];  // W_fx rows (this wave's 64 feat cols), K=64
#pragma unroll
    for (int kk = 0; kk < 2; ++kk)
#pragma unroll
      for (int nt = 0; nt < 4; ++nt)
        WfR[kk][nt] = cvt8(W_fx + ((wv * 4 + nt) * 16 + c15) * 64 + kk * 32 + qq * 8);
    float bout_r = b_out[wv * 16 + c15];
    float bfx_r[4];
#pragma unroll
    for (int nt = 0; nt < 4; ++nt) bfx_r[nt] = b_fx[(wv * 4 + nt) * 16 + c15];
    float bhx_r[4];
#pragma unroll
    for (int nt = 0; nt < 4; ++nt) bhx_r[nt] = b_hx[wv * 64 + nt * 16 + c15];

    int r = 0, rn = 1;
    for (int t = 0; t < SEQ; ++t) {
      // prefetch x[t+1] + msel[t+1] before the poll (plain cached loads)
      short8 xa[2][4];
      float mix = 0.f;
      if (t < SEQ - 1) {
        mix = msel[t + 1];
#pragma unroll
        for (int kb = 0; kb < 2; ++kb)
#pragma unroll
          for (int mt = 0; mt < 4; ++mt)
            xa[kb][mt] = cvt8v(x + ((t + 1) * 64 + mt * 16 + c15) * 64 + kb * 32 + qq * 8);
      }
      if (tid < 64) pollge(&hflag[tid * 16], (u32)t);
      __syncthreads();
      const u16* A = Abase + r * A_ELE;
      u16* An = Abase + rn * A_ELE;
      // copy h section (chunks 2048..6143 = 64KB) -> LDS via coherent loads,
      // frag layout preserved
#pragma unroll
      for (int it = 0; it < 16; ++it) {
        int idx = it * 256 + tid;
        *(short8*)(hlds + idx * 8) = ldc16(A + (2048 + idx) * 8);
      }
      __syncthreads();
      // GEMM1: d_pre = h @ W_hx^T ; wave wv owns dec cols [wv*64, wv*64+64)
      // full K=512 per wave (no cross-wave reduce); B streamed from L2 pack
      f32x4 acc1[4][4];
#pragma unroll
      for (int nt = 0; nt < 4; nt++)
#pragma unroll
        for (int mt = 0; mt < 4; mt++) acc1[nt][mt] = (f32x4){0.f, 0.f, 0.f, 0.f};
#pragma unroll 4
      for (int kb = 0; kb < 16; ++kb) {
        short8 ahf[4];
#pragma unroll
        for (int mt = 0; mt < 4; ++mt)
          ahf[mt] = *(const short8*)(hlds + ((kb * 4 + mt) * 64 + ln) * 8);
        short8 bw[4];
#pragma unroll
        for (int nt = 0; nt < 4; ++nt)
          bw[nt] = *(const short8*)(Whx_pack + ((kb * 16 + wv * 4 + nt) * 64 + ln) * 8);
#pragma unroll
        for (int nt = 0; nt < 4; ++nt)
#pragma unroll
          for (int mt = 0; mt < 4; ++mt)
            acc1[nt][mt] = __builtin_amdgcn_mfma_f32_16x16x32_bf16(ahf[mt], bw[nt], acc1[nt][mt], 0, 0, 0);
      }
      // tanh -> dlds[m][dec], pitch 264 (bank spread for frag re-reads)
#pragma unroll
      for (int nt = 0; nt < 4; ++nt)
#pragma unroll
        for (int mt = 0; mt < 4; ++mt)
#pragma unroll
          for (int r2 = 0; r2 < 4; ++r2) {
            int m = mt * 16 + qq * 4 + r2;
            int n = wv * 64 + nt * 16 + c15;
            dlds[m * 264 + n] = f2bf(fast_tanh(acc1[nt][mt][r2] + bhx_r[nt]));
          }
      __syncthreads();
      // GEMM2: y = d @ W_out^T ; wave wv owns out cols [wv*16, wv*16+16), full K=256
      f32x4 acc2[4];
#pragma unroll
      for (int mt = 0; mt < 4; mt++) acc2[mt] = (f32x4){0.f, 0.f, 0.f, 0.f};
#pragma unroll
      for (int kb = 0; kb < 8; ++kb) {
        short8 a2[4];
#pragma unroll
        for (int mt = 0; mt < 4; ++mt)
          a2[mt] = *(const short8*)(dlds + (mt * 16 + c15) * 264 + kb * 32 + qq * 8);
#pragma unroll
        for (int mt = 0; mt < 4; ++mt)
          acc2[mt] = __builtin_amdgcn_mfma_f32_16x16x32_bf16(a2[mt], Breg2[kb], acc2[mt], 0, 0, 0);
      }
#pragma unroll
      for (int mt = 0; mt < 4; ++mt)
#pragma unroll
        for (int r2 = 0; r2 < 4; ++r2) {
          float yv = acc2[mt][r2] + bout_r;
          int row = mt * 16 + qq * 4 + r2;
          out[t * 4096 + row * 64 + wv * 16 + c15] = yv;   // f32 output (plain)
          ystage[row * 80 + wv * 16 + c15] = f2bf(yv);
        }
      __syncthreads();
      if (t < SEQ - 1) {
        f32x4 au[4][4], tf[4][4];
#pragma unroll
        for (int nt = 0; nt < 4; nt++)
#pragma unroll
          for (int mt = 0; mt < 4; mt++) {
            au[nt][mt] = (f32x4){0.f, 0.f, 0.f, 0.f};
            tf[nt][mt] = (f32x4){0.f, 0.f, 0.f, 0.f};
          }
#pragma unroll
        for (int kb = 0; kb < 2; ++kb) {
          int koff = kb * 32 + qq * 8;
          short8 ya[4];
#pragma unroll
          for (int mt = 0; mt < 4; mt++)
            ya[mt] = *(const short8*)(ystage + (mt * 16 + c15) * 80 + koff);
#pragma unroll
          for (int nt = 0; nt < 4; nt++)
#pragma unroll
            for (int mt = 0; mt < 4; mt++) {
              au[nt][mt] = __builtin_amdgcn_mfma_f32_16x16x32_bf16(ya[mt], WfR[kb][nt], au[nt][mt], 0, 0, 0);
              tf[nt][mt] = __builtin_amdgcn_mfma_f32_16x16x32_bf16(xa[kb][mt], WfR[kb][nt], tf[nt][mt], 0, 0, 0);
            }
        }
#pragma unroll
        for (int nt = 0; nt < 4; nt++)
#pragma unroll
          for (int mt = 0; mt < 4; mt++)
#pragma unroll
            for (int r2 = 0; r2 < 4; r2++) {
              float f = mix * fast_tanh(au[nt][mt][r2] + bfx_r[nt]) +
                        (1.f - mix) * fast_tanh(tf[nt][mt][r2] + bfx_r[nt]);
              int row = mt * 16 + qq * 4 + r2;
              fstage[row * 264 + (wv * 4 + nt) * 16 + c15] = f2bf(f);
            }
        __syncthreads();
#pragma unroll
        for (int it = 0; it < 8; ++it) {       // fstage -> An feat section, coherent
          int chunk = it * 256 + tid;
          int kb = chunk >> 8, l = chunk & 63;
          int m = ((chunk >> 6) & 3) * 16 + (l & 15);
          int k = kb * 32 + (l >> 4) * 8;
          V16 v; v.s = *(const short8*)(fstage + m * 264 + k);
          stc16(An + chunk * 8, v.q);
        }
        VMCNT0();
        __syncthreads();
        if (tid == 0) setflag(fcv, (u32)(t + 1));
      }
      r = rn; rn = (rn == 2) ? 0 : rn + 1;
    }
  }
}

extern "C" void kernel_launch(void* const* d_in, const int* in_sizes, int n_in,
                              void* d_out, int out_size, void* d_ws, size_t ws_size,
                              hipStream_t stream) {
  const float* x     = (const float*)d_in[0];
  const float* msel  = (const float*)d_in[1];
  const float* W_fx  = (const float*)d_in[2];
  const float* b_fx  = (const float*)d_in[3];
  const float* W_ih  = (const float*)d_in[4];
  const float* W_hh  = (const float*)d_in[5];
  const float* b_ih  = (const float*)d_in[6];
  const float* b_hh  = (const float*)d_in[7];
  const float* W_hx  = (const float*)d_in[8];
  const float* b_hx  = (const float*)d_in[9];
  const float* W_out = (const float*)d_in[10];
  const float* b_out = (const float*)d_in[11];

  uint8_t* ws = (uint8_t*)d_ws;
  u16* Abase    = (u16*)ws;                 // ring of 3 x 98304 B
  u16* Whx_pack = (u16*)(ws + 294912);      // 262144 B (bf16 frag-packed W_hx)
  u32* flags    = (u32*)(ws + 557056);      // 4672 B

  prep_kernel<<<73, 256, 0, stream>>>(x, W_fx, b_fx, W_hx, Abase, Whx_pack, flags);
  rnn_kernel<<<NWG, 256, 0, stream>>>(x, msel, W_fx, b_fx, W_ih, W_hh, b_ih, b_hh,
                                      W_hx, b_hx, W_out, b_out,
                                      (float*)d_out, Abase, Whx_pack, flags);
}

// Round 3
// 3547.783 us; speedup vs baseline: 1.7203x; 1.6438x over previous
//
#include <hip/hip_runtime.h>
#include <stdint.h>

typedef unsigned short u16;
typedef unsigned int u32;
typedef unsigned long long u64;
typedef __attribute__((ext_vector_type(8))) short short8;   // 8 x bf16
typedef __attribute__((ext_vector_type(4))) float f32x4;
typedef __attribute__((ext_vector_type(4))) int int4v;

#define SEQ 256
#define GATE_WGS 64
#define NWG 65          // 64 gate (16 of them also produce d slices) + 1 y
#define A_ELE 49152     // elements per A ring slot (bf16): feat[16K] + h[32K]
#define D_ELE 16384

__device__ __forceinline__ u16 f2bf(float f) {
  u32 u = __float_as_uint(f);
  u += 0x7FFFu + ((u >> 16) & 1u);
  return (u16)(u >> 16);
}
__device__ __forceinline__ short8 cvt8(const float* __restrict__ p) {
  short8 r;
#pragma unroll
  for (int j = 0; j < 8; ++j) r[j] = (short)f2bf(p[j]);
  return r;
}
__device__ __forceinline__ short8 cvt8v(const float* __restrict__ p) {  // 2x float4
  f32x4 a = *(const f32x4*)p, b = *(const f32x4*)(p + 4);
  short8 r;
#pragma unroll
  for (int j = 0; j < 4; ++j) { r[j] = (short)f2bf(a[j]); r[4 + j] = (short)f2bf(b[j]); }
  return r;
}
__device__ __forceinline__ float fast_tanh(float x) {
  return 1.0f - 2.0f / (1.0f + __expf(2.0f * x));
}
__device__ __forceinline__ float fast_sig(float x) {
  return 1.0f / (1.0f + __expf(-x));
}

union V16 { short8 s; u64 q[2]; };
// device-coherent 16B load/store (bypass L1/L2 -> coherence point), fence-free
__device__ __forceinline__ short8 ldc16(const u16* p) {
  V16 v;
  v.q[0] = __hip_atomic_load((const u64*)p,     __ATOMIC_RELAXED, __HIP_MEMORY_SCOPE_AGENT);
  v.q[1] = __hip_atomic_load((const u64*)p + 1, __ATOMIC_RELAXED, __HIP_MEMORY_SCOPE_AGENT);
  return v.s;
}
__device__ __forceinline__ void stc16(u16* p, const u64* s) {
  __hip_atomic_store((u64*)p,     s[0], __ATOMIC_RELAXED, __HIP_MEMORY_SCOPE_AGENT);
  __hip_atomic_store((u64*)p + 1, s[1], __ATOMIC_RELAXED, __HIP_MEMORY_SCOPE_AGENT);
}
__device__ __forceinline__ void pollge(u32* p, u32 v) {
  while (__hip_atomic_load(p, __ATOMIC_RELAXED, __HIP_MEMORY_SCOPE_AGENT) < v) {}
}
__device__ __forceinline__ void setflag(u32* p, u32 v) {
  __hip_atomic_store(p, v, __ATOMIC_RELAXED, __HIP_MEMORY_SCOPE_AGENT);
}
// per-wave store drain: prior coherent stores reach coherence point before flag
#define VMCNT0() asm volatile("s_waitcnt vmcnt(0)" ::: "memory")

// ---------------------------------------------------------------------------
// Prep: feat_0 -> Abuf slot0 feat section; zero slot0 h section; zero flags.
// A-frag chunk layout: chunk = (kb*4 + mt)*64 + lane; lane holds
// A[m = mt*16 + (lane&15)][k = kb*32 + (lane>>4)*8 + j], j=0..7.
// ---------------------------------------------------------------------------
__global__ void prep_kernel(const float* __restrict__ x, const float* __restrict__ W_fx,
                            const float* __restrict__ b_fx,
                            u16* __restrict__ Abuf0, u32* __restrict__ flags) {
  int b = blockIdx.x, tid = threadIdx.x;
  if (b < 64) {
    int gidx = b * 256 + tid;          // 16384 elements of feat_0 [64][256]
    int chunk = gidx >> 3, j = gidx & 7;
    int kb = chunk >> 8, mt = (chunk >> 6) & 3, l = chunk & 63;
    int m = mt * 16 + (l & 15);
    int c = kb * 32 + (l >> 4) * 8 + j;
    float s = b_fx[c];
    const float* xr = x + m * 64;      // t = 0
    const float* wr = W_fx + c * 64;
    for (int k = 0; k < 64; ++k) s += xr[k] * wr[k];
    Abuf0[chunk * 8 + j] = f2bf(fast_tanh(s));
  } else {
    for (int it = 0; it < 16; ++it) {  // zero h-section of slot0: chunks 2048..6143
      int chunk = it * 256 + tid;
      *(int4v*)(Abuf0 + (2048 + chunk) * 8) = (int4v){0, 0, 0, 0};
    }
    for (int k = 0; k < 6; ++k) {      // zero flags: hflag[1024] dflag[256] fcv
      int i = k * 256 + tid;
      if (i < 1296) flags[i] = 0u;
    }
  }
}

// ---------------------------------------------------------------------------
// Persistent recurrent kernel. 65 WGs x 256 threads. Fence-free coherent flow:
//   hflag[wg] = t+1 after gate wg stored h_{t+1} ; consumers poll >= t for h_t
//   dflag[wg] = t+1 after gate wg (<16) stored its d_t slice ; y polls >= t+1
//   fc        = t+1 after y stored feat_{t+1}    ; gates poll >= t for feat_t
// d is computed INSIDE gate WGs 0..15 from the already-loaded h fragments:
// removes the separate d-WG hop from the feat chain (3 hops -> 2).
// ---------------------------------------------------------------------------
__global__ void __launch_bounds__(256, 1)
rnn_kernel(const float* __restrict__ x, const float* __restrict__ msel,
           const float* __restrict__ W_fx, const float* __restrict__ b_fx,
           const float* __restrict__ W_ih, const float* __restrict__ W_hh,
           const float* __restrict__ b_ih, const float* __restrict__ b_hh,
           const float* __restrict__ W_hx, const float* __restrict__ b_hx,
           const float* __restrict__ W_out, const float* __restrict__ b_out,
           float* __restrict__ out,
           u16* __restrict__ Abase, u16* __restrict__ dbase,
           u32* __restrict__ flags) {
  __shared__ __attribute__((aligned(16))) char smem[109568];
  const int wgid = blockIdx.x;
  const int tid = threadIdx.x;
  const int wv = tid >> 6, ln = tid & 63;
  u32* hflag = flags;          // stride 16 u32 (64B lines)
  u32* dflag = flags + 1024;   // 16 used, stride 16
  u32* fcv   = flags + 1280;

  if (wgid < GATE_WGS) {
    // ===== gate WG: 8 hidden units -> 32 gate cols; B-frags in REGISTERS =====
    const int wg = wgid;
    float* red = (float*)smem;                 // [4 wv][8 tile][64][4] = 32KB
    u16* hstage = (u16*)(smem + 32768);        // [4 mt][16 m15][8 u] = 1KB
    float* redD = (float*)(smem + 33792);      // [3 w][4 mt][64][4] = 12KB
    u16* dstage = (u16*)(smem + 46080);        // [4 mt][32 lane32][8 j] = 2KB
    short8 Breg[6][2];
#pragma unroll
    for (int kk = 0; kk < 6; ++kk) {
      int kb = wv * 6 + kk;
#pragma unroll
      for (int nt = 0; nt < 2; ++nt) {
        int n = ln & 15, q = ln >> 4;
        int gate = nt * 2 + (n >> 3), unit = n & 7;
        int row = gate * 512 + wg * 8 + unit;
        int k = kb * 32 + q * 8;
        const float* src = (k < 256) ? (W_ih + row * 256 + k) : (W_hh + row * 512 + (k - 256));
        Breg[kk][nt] = cvt8(src);
      }
    }
    float bsum_r[2][4];
#pragma unroll
    for (int it = 0; it < 2; ++it) {
      int u = (it * 256 + tid) & 7;
#pragma unroll
      for (int g = 0; g < 4; ++g) {
        int row = g * 512 + wg * 8 + u;
        bsum_r[it][g] = b_ih[row] + b_hh[row];
      }
    }
    // d-producer extras (WGs 0..15): B-frags for W_hx cols [wg*16, wg*16+16)
    const bool DWG = (wg < 16);
    short8 BregD[6];
    float bhx_r = 0.f;
    if (DWG) {
      bhx_r = b_hx[wg * 16 + (tid & 15)];
#pragma unroll
      for (int kk = 0; kk < 6; ++kk) {
        int kb = wv * 6 + kk;                  // h k-blocks are kb 8..23
        if (kb >= 8)
          BregD[kk] = cvt8(W_hx + (wg * 16 + (ln & 15)) * 512 + (kb - 8) * 32 + (ln >> 4) * 8);
      }
    }
    float creg[2] = {0.f, 0.f};
    const int kbW = 8 + (wg >> 2), qW = wg & 3;   // this WG's h region
    int r = 0, rn = 1;
    for (int t = 0; t < SEQ; ++t) {
      if (tid < 64) pollge(&hflag[tid * 16], (u32)t);
      else if (tid == 64) pollge(fcv, (u32)t);
      __syncthreads();
      const u16* A = Abase + r * A_ELE;
      u16* An = Abase + rn * A_ELE;
      short8 a[6][4];
#pragma unroll
      for (int kk = 0; kk < 6; ++kk)
#pragma unroll
        for (int mt = 0; mt < 4; ++mt)
          a[kk][mt] = ldc16(A + (((wv * 6 + kk) * 4 + mt) * 64 + ln) * 8);
      f32x4 acc[2][4];
#pragma unroll
      for (int nt = 0; nt < 2; nt++)
#pragma unroll
        for (int mt = 0; mt < 4; mt++) acc[nt][mt] = (f32x4){0.f, 0.f, 0.f, 0.f};
#pragma unroll
      for (int kk = 0; kk < 6; ++kk)
#pragma unroll
        for (int nt = 0; nt < 2; nt++)
#pragma unroll
          for (int mt = 0; mt < 4; mt++)
            acc[nt][mt] = __builtin_amdgcn_mfma_f32_16x16x32_bf16(a[kk][mt], Breg[kk][nt], acc[nt][mt], 0, 0, 0);
      // d partial GEMM from the SAME h fragments (no extra loads)
      f32x4 accD[4];
      if (DWG) {
#pragma unroll
        for (int mt = 0; mt < 4; mt++) accD[mt] = (f32x4){0.f, 0.f, 0.f, 0.f};
#pragma unroll
        for (int kk = 0; kk < 6; ++kk) {
          if (wv * 6 + kk >= 8) {
#pragma unroll
            for (int mt = 0; mt < 4; mt++)
              accD[mt] = __builtin_amdgcn_mfma_f32_16x16x32_bf16(a[kk][mt], BregD[kk], accD[mt], 0, 0, 0);
          }
        }
      }
      // one-shot 4-wave reduction staging
#pragma unroll
      for (int nt = 0; nt < 2; nt++)
#pragma unroll
        for (int mt = 0; mt < 4; mt++)
          *(f32x4*)(red + ((wv * 8 + nt * 4 + mt) * 64 + ln) * 4) = acc[nt][mt];
      if (DWG && wv >= 1) {
#pragma unroll
        for (int mt = 0; mt < 4; mt++)
          *(f32x4*)(redD + (((wv - 1) * 4 + mt) * 64 + ln) * 4) = accD[mt];
      }
      __syncthreads();
      if (DWG) {
        // d finalize: 1024 outputs (64 m x 16 c), 4/thread; c = tid&15 fixed
        int m15 = tid >> 4, c = tid & 15;
        int qq = m15 >> 2, reg = m15 & 3;
        int lanei = qq * 16 + c;
#pragma unroll
        for (int it = 0; it < 4; ++it) {       // it == mt, m = it*16 + m15
          float s = bhx_r;
#pragma unroll
          for (int w = 0; w < 3; ++w) s += redD[((w * 4 + it) * 64 + lanei) * 4 + reg];
          dstage[(it * 32 + ((tid >> 3) & 1) * 16 + m15) * 8 + (tid & 7)] = f2bf(fast_tanh(s));
        }
        __syncthreads();
      }
      // wave 1 publishes the d slice (overlapped with LSTM compute below)
      u16* dbufR = dbase + (t & 1) * D_ELE;
      if (DWG && wv == 1) {
#pragma unroll
        for (int s2 = 0; s2 < 2; ++s2) {       // 128 chunks over 64 threads
          int c128 = (tid - 64) + s2 * 64;
          int mtd = c128 >> 5, lane32 = c128 & 31;
          int chunk = ((wg >> 1) * 4 + mtd) * 64 + (wg & 1) * 32 + lane32;
          stc16(dbufR + chunk * 8, (const u64*)(dstage + c128 * 8));
        }
      }
      // LSTM cell: 512 (m,u) items, 2/thread; sum 4 wave-partials inline
#pragma unroll
      for (int it = 0; it < 2; ++it) {
        int item = it * 256 + tid;
        int m = item >> 3, u = item & 7;
        int mt = m >> 4, lq = ((m & 15) >> 2) * 16, reg = m & 3;
        float g4[4];
#pragma unroll
        for (int g = 0; g < 4; ++g) {
          float s = bsum_r[it][g];
          int base = ((g >> 1) * 4 + mt) * 64 + lq + (g & 1) * 8 + u;
#pragma unroll
          for (int w = 0; w < 4; ++w) s += red[(w * 8 * 64 + base) * 4 + reg];
          g4[g] = s;
        }
        float ii = fast_sig(g4[0]), ff = fast_sig(g4[1]);
        float gg = fast_tanh(g4[2]), oo = fast_sig(g4[3]);
        float cn = ff * creg[it] + ii * gg;
        creg[it] = cn;
        float h = oo * fast_tanh(cn);
        hstage[(mt * 16 + (m & 15)) * 8 + u] = f2bf(h);
      }
      if (DWG && wv == 1) {   // drain d stores (latency hidden under LSTM), flag
        VMCNT0();
        if (tid == 64) setflag(&dflag[wg * 16], (u32)(t + 1));
      }
      __syncthreads();
      if (tid < 64) {   // 16B coherent stores of this WG's 1KB h region
        int mt2 = tid >> 4, m15b = tid & 15;
        u16* dst = An + (((kbW * 4 + mt2) * 64 + qW * 16 + m15b) * 8);
        stc16(dst, (const u64*)(hstage + tid * 8));
        VMCNT0();
        if (tid == 0) setflag(&hflag[wg * 16], (u32)(t + 1));
      }
      r = rn; rn = (rn == 2) ? 0 : rn + 1;
    }
  } else {
    // ===== y WG: y = d@Wout^T + b_out; feat_{t+1} = mix*fe(y)+(1-mix)*fe(x) =====
    float* red = (float*)smem;                 // [4 wv][16 tile][64][4] = 64KB
    u16* ystage = (u16*)(smem + 65536);        // [64][80] = 10240B
    u16* fstage = (u16*)(smem + 75776);        // [64][264] = 33792B
    const int c15 = ln & 15, qq = ln >> 4;
    short8 WoR[2][4], WfR[2][4];
#pragma unroll
    for (int kk = 0; kk < 2; ++kk) {
      int koffo = (wv * 2 + kk) * 32 + qq * 8;   // W_out K-offset (K=256)
      int kofff = kk * 32 + qq * 8;              // W_fx K-offset (K=64)
#pragma unroll
      for (int nt = 0; nt < 4; ++nt) {
        WoR[kk][nt] = cvt8(W_out + (nt * 16 + c15) * 256 + koffo);
        WfR[kk][nt] = cvt8(W_fx + ((wv * 4 + nt) * 16 + c15) * 64 + kofff);
      }
    }
    float bout_r = b_out[wv * 16 + c15];
    float bfx_r[4];
#pragma unroll
    for (int nt = 0; nt < 4; ++nt) bfx_r[nt] = b_fx[(wv * 4 + nt) * 16 + c15];

    int rn = 1;
    for (int t = 0; t < SEQ; ++t) {
      // prefetch x[t+1] + msel[t+1] before the poll (plain cached loads)
      short8 xa[2][4];
      float mix = 0.f;
      if (t < SEQ - 1) {
        mix = msel[t + 1];
#pragma unroll
        for (int kb = 0; kb < 2; ++kb)
#pragma unroll
          for (int mt = 0; mt < 4; ++mt)
            xa[kb][mt] = cvt8v(x + ((t + 1) * 64 + mt * 16 + c15) * 64 + kb * 32 + qq * 8);
      }
      if (tid < 16) pollge(&dflag[tid * 16], (u32)(t + 1));
      __syncthreads();
      const u16* dbufR = dbase + (t & 1) * D_ELE;
      u16* An = Abase + rn * A_ELE;
      short8 da[2][4];
#pragma unroll
      for (int kk = 0; kk < 2; ++kk)
#pragma unroll
        for (int mt = 0; mt < 4; ++mt)
          da[kk][mt] = ldc16(dbufR + (((wv * 2 + kk) * 4 + mt) * 64 + ln) * 8);
      f32x4 acc[4][4];
#pragma unroll
      for (int nt = 0; nt < 4; nt++)
#pragma unroll
        for (int mt = 0; mt < 4; mt++) acc[nt][mt] = (f32x4){0.f, 0.f, 0.f, 0.f};
#pragma unroll
      for (int kk = 0; kk < 2; ++kk)
#pragma unroll
        for (int nt = 0; nt < 4; nt++)
#pragma unroll
          for (int mt = 0; mt < 4; mt++)
            acc[nt][mt] = __builtin_amdgcn_mfma_f32_16x16x32_bf16(da[kk][mt], WoR[kk][nt], acc[nt][mt], 0, 0, 0);
#pragma unroll
      for (int nt = 0; nt < 4; nt++)
#pragma unroll
        for (int mt = 0; mt < 4; mt++)
          *(f32x4*)(red + ((wv * 16 + nt * 4 + mt) * 64 + ln) * 4) = acc[nt][mt];
      __syncthreads();
      // wave wv finalizes output cols [wv*16, wv*16+16)
#pragma unroll
      for (int mt = 0; mt < 4; ++mt) {
        f32x4 s = (f32x4){0.f, 0.f, 0.f, 0.f};
#pragma unroll
        for (int w2 = 0; w2 < 4; ++w2)
          s += *(const f32x4*)(red + ((w2 * 16 + wv * 4 + mt) * 64 + ln) * 4);
#pragma unroll
        for (int r2 = 0; r2 < 4; ++r2) {
          float yv = s[r2] + bout_r;
          int row = mt * 16 + qq * 4 + r2;
          out[t * 4096 + row * 64 + wv * 16 + c15] = yv;   // f32 output (plain)
          ystage[row * 80 + wv * 16 + c15] = f2bf(yv);
        }
      }
      __syncthreads();
      if (t < SEQ - 1) {
        f32x4 au[4][4], tf[4][4];
#pragma unroll
        for (int nt = 0; nt < 4; nt++)
#pragma unroll
          for (int mt = 0; mt < 4; mt++) {
            au[nt][mt] = (f32x4){0.f, 0.f, 0.f, 0.f};
            tf[nt][mt] = (f32x4){0.f, 0.f, 0.f, 0.f};
          }
#pragma unroll
        for (int kb = 0; kb < 2; ++kb) {
          int koff = kb * 32 + qq * 8;
          short8 ya[4];
#pragma unroll
          for (int mt = 0; mt < 4; mt++)
            ya[mt] = *(const short8*)(ystage + (mt * 16 + c15) * 80 + koff);
#pragma unroll
          for (int nt = 0; nt < 4; nt++)
#pragma unroll
            for (int mt = 0; mt < 4; mt++) {
              au[nt][mt] = __builtin_amdgcn_mfma_f32_16x16x32_bf16(ya[mt], WfR[kb][nt], au[nt][mt], 0, 0, 0);
              tf[nt][mt] = __builtin_amdgcn_mfma_f32_16x16x32_bf16(xa[kb][mt], WfR[kb][nt], tf[nt][mt], 0, 0, 0);
            }
        }
#pragma unroll
        for (int nt = 0; nt < 4; nt++)
#pragma unroll
          for (int mt = 0; mt < 4; mt++)
#pragma unroll
            for (int r2 = 0; r2 < 4; r2++) {
              float f = mix * fast_tanh(au[nt][mt][r2] + bfx_r[nt]) +
                        (1.f - mix) * fast_tanh(tf[nt][mt][r2] + bfx_r[nt]);
              int row = mt * 16 + qq * 4 + r2;
              fstage[row * 264 + (wv * 4 + nt) * 16 + c15] = f2bf(f);
            }
        __syncthreads();
#pragma unroll
        for (int it = 0; it < 8; ++it) {       // fstage -> An feat section, coherent
          int chunk = it * 256 + tid;
          int kb = chunk >> 8, l = chunk & 63;
          int m = ((chunk >> 6) & 3) * 16 + (l & 15);
          int k = kb * 32 + (l >> 4) * 8;
          V16 v; v.s = *(const short8*)(fstage + m * 264 + k);
          stc16(An + chunk * 8, v.q);
        }
        VMCNT0();
        __syncthreads();
        if (tid == 0) setflag(fcv, (u32)(t + 1));
      }
      rn = (rn == 2) ? 0 : rn + 1;
    }
  }
}

extern "C" void kernel_launch(void* const* d_in, const int* in_sizes, int n_in,
                              void* d_out, int out_size, void* d_ws, size_t ws_size,
                              hipStream_t stream) {
  const float* x     = (const float*)d_in[0];
  const float* msel  = (const float*)d_in[1];
  const float* W_fx  = (const float*)d_in[2];
  const float* b_fx  = (const float*)d_in[3];
  const float* W_ih  = (const float*)d_in[4];
  const float* W_hh  = (const float*)d_in[5];
  const float* b_ih  = (const float*)d_in[6];
  const float* b_hh  = (const float*)d_in[7];
  const float* W_hx  = (const float*)d_in[8];
  const float* b_hx  = (const float*)d_in[9];
  const float* W_out = (const float*)d_in[10];
  const float* b_out = (const float*)d_in[11];

  uint8_t* ws = (uint8_t*)d_ws;
  u16* Abase = (u16*)ws;                    // ring of 3 x 98304 B
  u16* dbase = (u16*)(ws + 294912);         // ring of 2 x 32768 B
  u32* flags = (u32*)(ws + 360448);         // 5184 B

  prep_kernel<<<65, 256, 0, stream>>>(x, W_fx, b_fx, Abase, flags);
  rnn_kernel<<<NWG, 256, 0, stream>>>(x, msel, W_fx, b_fx, W_ih, W_hh, b_ih, b_hh,
                                      W_hx, b_hx, W_out, b_out,
                                      (float*)d_out, Abase, dbase, flags);
}

// Round 4
// 2982.205 us; speedup vs baseline: 2.0466x; 1.1897x over previous
//
#include <hip/hip_runtime.h>
#include <stdint.h>

typedef unsigned short u16;
typedef unsigned int u32;
typedef unsigned long long u64;
typedef __attribute__((ext_vector_type(8))) short short8;   // 8 x bf16
typedef __attribute__((ext_vector_type(4))) float f32x4;
typedef __attribute__((ext_vector_type(4))) int int4v;

#define SEQ 256
#define GATE_WGS 64
#define D_WGS 8
#define NWG 73          // 64 gate + 8 d + 1 y
#define A_ELE 49152     // elements per A ring slot (bf16)
#define D_ELE 16384

__device__ __forceinline__ u16 f2bf(float f) {
  u32 u = __float_as_uint(f);
  u += 0x7FFFu + ((u >> 16) & 1u);
  return (u16)(u >> 16);
}
__device__ __forceinline__ short8 cvt8(const float* __restrict__ p) {
  short8 r;
#pragma unroll
  for (int j = 0; j < 8; ++j) r[j] = (short)f2bf(p[j]);
  return r;
}
__device__ __forceinline__ short8 cvt8v(const float* __restrict__ p) {  // 2x float4
  f32x4 a = *(const f32x4*)p, b = *(const f32x4*)(p + 4);
  short8 r;
#pragma unroll
  for (int j = 0; j < 4; ++j) { r[j] = (short)f2bf(a[j]); r[4 + j] = (short)f2bf(b[j]); }
  return r;
}
__device__ __forceinline__ float fast_tanh(float x) {
  return 1.0f - 2.0f / (1.0f + __expf(2.0f * x));
}
__device__ __forceinline__ float fast_sig(float x) {
  return 1.0f / (1.0f + __expf(-x));
}

union V16 { short8 s; u64 q[2]; };
// device-coherent 16B load/store (bypass L1/L2 -> L3), fence-free data flow
__device__ __forceinline__ short8 ldc16(const u16* p) {
  V16 v;
  v.q[0] = __hip_atomic_load((const u64*)p,     __ATOMIC_RELAXED, __HIP_MEMORY_SCOPE_AGENT);
  v.q[1] = __hip_atomic_load((const u64*)p + 1, __ATOMIC_RELAXED, __HIP_MEMORY_SCOPE_AGENT);
  return v.s;
}
__device__ __forceinline__ void stc16(u16* p, const u64* s) {
  __hip_atomic_store((u64*)p,     s[0], __ATOMIC_RELAXED, __HIP_MEMORY_SCOPE_AGENT);
  __hip_atomic_store((u64*)p + 1, s[1], __ATOMIC_RELAXED, __HIP_MEMORY_SCOPE_AGENT);
}
__device__ __forceinline__ void pollge(u32* p, u32 v) {
  while (__hip_atomic_load(p, __ATOMIC_RELAXED, __HIP_MEMORY_SCOPE_AGENT) < v) {}
}
__device__ __forceinline__ void setflag(u32* p, u32 v) {
  __hip_atomic_store(p, v, __ATOMIC_RELAXED, __HIP_MEMORY_SCOPE_AGENT);
}
// per-wave store drain: prior sc0sc1 stores reach coherence point before flag
#define VMCNT0() asm volatile("s_waitcnt vmcnt(0)" ::: "memory")

// ---------------------------------------------------------------------------
// Prep: feat_0 -> Abuf slot0 feat section; zero slot0 h section; zero flags.
// A-frag chunk layout: chunk = (kb*4 + mt)*64 + lane; lane holds
// A[m = mt*16 + (lane&15)][k = kb*32 + (lane>>4)*8 + j], j=0..7.
// ---------------------------------------------------------------------------
__global__ void prep_kernel(const float* __restrict__ x, const float* __restrict__ W_fx,
                            const float* __restrict__ b_fx,
                            u16* __restrict__ Abuf0, u32* __restrict__ flags) {
  int b = blockIdx.x, tid = threadIdx.x;
  if (b < 64) {
    int gidx = b * 256 + tid;          // 16384 elements of feat_0 [64][256]
    int chunk = gidx >> 3, j = gidx & 7;
    int kb = chunk >> 8, mt = (chunk >> 6) & 3, l = chunk & 63;
    int m = mt * 16 + (l & 15);
    int c = kb * 32 + (l >> 4) * 8 + j;
    float s = b_fx[c];
    const float* xr = x + m * 64;      // t = 0
    const float* wr = W_fx + c * 64;
    for (int k = 0; k < 64; ++k) s += xr[k] * wr[k];
    Abuf0[chunk * 8 + j] = f2bf(fast_tanh(s));
  } else {
    for (int it = 0; it < 16; ++it) {  // zero h-section of slot0: chunks 2048..6143
      int chunk = it * 256 + tid;
      *(int4v*)(Abuf0 + (2048 + chunk) * 8) = (int4v){0, 0, 0, 0};
    }
    for (int k = 0; k < 5; ++k) {      // zero flags: dflag, fcv, hcnt[4]
      int i = k * 256 + tid;
      if (i < 1280) flags[i] = 0u;
    }
  }
}

// ---------------------------------------------------------------------------
// Persistent recurrent kernel. 73 WGs x 256 threads. Fence-free coherent flow:
//   hcnt[j] += 1 (j=wg&3) after gate wg stored h_{t+1}; consumers poll
//                hcnt[j] >= 16*t for "all h_t stored" (narrow 4-line poll)
//   dflag[dw] = t+1 after d dw stored d_t        ; y polls >= t+1
//   fc        = t+1 after y stored feat_{t+1}    ; gates poll >= t for feat_t
// ---------------------------------------------------------------------------
__global__ void __launch_bounds__(256, 1)
rnn_kernel(const float* __restrict__ x, const float* __restrict__ msel,
           const float* __restrict__ W_fx, const float* __restrict__ b_fx,
           const float* __restrict__ W_ih, const float* __restrict__ W_hh,
           const float* __restrict__ b_ih, const float* __restrict__ b_hh,
           const float* __restrict__ W_hx, const float* __restrict__ b_hx,
           const float* __restrict__ W_out, const float* __restrict__ b_out,
           float* __restrict__ out,
           u16* __restrict__ Abase, u16* __restrict__ dbase,
           u32* __restrict__ flags) {
  __shared__ __attribute__((aligned(16))) char smem[109568];
  const int wgid = blockIdx.x;
  const int tid = threadIdx.x;
  const int wv = tid >> 6, ln = tid & 63;
  u32* dflag = flags + 1024;   // stride 16 u32 (64B lines)
  u32* fcv   = flags + 1152;
  u32* hcnt  = flags + 1168;   // 4 counters, stride 16 (lines 1168/1184/1200/1216)

  if (wgid < GATE_WGS) {
    // ===== gate WG: 8 hidden units -> 32 gate cols; B-frags in REGISTERS =====
    const int wg = wgid;
    float* red = (float*)smem;                 // [4 wv][8 tile][64][4] = 32KB
    u16* hstage = (u16*)(smem + 32768);        // [4 mt][16 m15][8 u] = 1KB
    short8 Breg[6][2];
#pragma unroll
    for (int kk = 0; kk < 6; ++kk) {
      int kb = wv * 6 + kk;
#pragma unroll
      for (int nt = 0; nt < 2; ++nt) {
        int n = ln & 15, q = ln >> 4;
        int gate = nt * 2 + (n >> 3), unit = n & 7;
        int row = gate * 512 + wg * 8 + unit;
        int k = kb * 32 + q * 8;
        const float* src = (k < 256) ? (W_ih + row * 256 + k) : (W_hh + row * 512 + (k - 256));
        Breg[kk][nt] = cvt8(src);
      }
    }
    float bsum_r[2][4];
#pragma unroll
    for (int it = 0; it < 2; ++it) {
      int u = (it * 256 + tid) & 7;
#pragma unroll
      for (int g = 0; g < 4; ++g) {
        int row = g * 512 + wg * 8 + u;
        bsum_r[it][g] = b_ih[row] + b_hh[row];
      }
    }
    float creg[2] = {0.f, 0.f};
    const int kbW = 8 + (wg >> 2), qW = wg & 3;   // this WG's h region
    int r = 0, rn = 1;
    for (int t = 0; t < SEQ; ++t) {
      if (tid < 4) pollge(&hcnt[tid * 16], (u32)(16 * t));
      else if (tid == 64) pollge(fcv, (u32)t);
      __syncthreads();
      const u16* A = Abase + r * A_ELE;
      u16* An = Abase + rn * A_ELE;
      short8 a[6][4];
#pragma unroll
      for (int kk = 0; kk < 6; ++kk)
#pragma unroll
        for (int mt = 0; mt < 4; ++mt)
          a[kk][mt] = ldc16(A + (((wv * 6 + kk) * 4 + mt) * 64 + ln) * 8);
      f32x4 acc[2][4];
#pragma unroll
      for (int nt = 0; nt < 2; nt++)
#pragma unroll
        for (int mt = 0; mt < 4; mt++) acc[nt][mt] = (f32x4){0.f, 0.f, 0.f, 0.f};
#pragma unroll
      for (int kk = 0; kk < 6; ++kk)
#pragma unroll
        for (int nt = 0; nt < 2; nt++)
#pragma unroll
          for (int mt = 0; mt < 4; mt++)
            acc[nt][mt] = __builtin_amdgcn_mfma_f32_16x16x32_bf16(a[kk][mt], Breg[kk][nt], acc[nt][mt], 0, 0, 0);
      // one-shot 4-wave reduction staging
#pragma unroll
      for (int nt = 0; nt < 2; nt++)
#pragma unroll
        for (int mt = 0; mt < 4; mt++)
          *(f32x4*)(red + ((wv * 8 + nt * 4 + mt) * 64 + ln) * 4) = acc[nt][mt];
      __syncthreads();
      // LSTM cell: 512 (m,u) items, 2/thread; sum 4 wave-partials inline
#pragma unroll
      for (int it = 0; it < 2; ++it) {
        int item = it * 256 + tid;
        int m = item >> 3, u = item & 7;
        int mt = m >> 4, lq = ((m & 15) >> 2) * 16, reg = m & 3;
        float g4[4];
#pragma unroll
        for (int g = 0; g < 4; ++g) {
          float s = bsum_r[it][g];
          int base = ((g >> 1) * 4 + mt) * 64 + lq + (g & 1) * 8 + u;
#pragma unroll
          for (int w = 0; w < 4; ++w) s += red[(w * 8 * 64 + base) * 4 + reg];
          g4[g] = s;
        }
        float ii = fast_sig(g4[0]), ff = fast_sig(g4[1]);
        float gg = fast_tanh(g4[2]), oo = fast_sig(g4[3]);
        float cn = ff * creg[it] + ii * gg;
        creg[it] = cn;
        float h = oo * fast_tanh(cn);
        hstage[(mt * 16 + (m & 15)) * 8 + u] = f2bf(h);
      }
      __syncthreads();
      if (tid < 64) {   // 16B coherent stores of this WG's 1KB h region
        int mt2 = tid >> 4, m15 = tid & 15;
        u16* dst = An + (((kbW * 4 + mt2) * 64 + qW * 16 + m15) * 8);
        stc16(dst, (const u64*)(hstage + tid * 8));
        VMCNT0();
        if (tid == 0)
          (void)__hip_atomic_fetch_add(&hcnt[(wg & 3) * 16], 1u,
                                       __ATOMIC_RELAXED, __HIP_MEMORY_SCOPE_AGENT);
      }
      r = rn; rn = (rn == 2) ? 0 : rn + 1;
    }
  } else if (wgid < GATE_WGS + D_WGS) {
    // ===== d WG: d = tanh(h @ Whx^T + b_hx), 32 DEC cols; B in registers =====
    const int dw = wgid - GATE_WGS;
    float* red = (float*)smem;                 // 32KB
    u16* dstage = (u16*)(smem + 32768);        // [4 mt][4 q][16 m15][8 j] = 4KB
    short8 Breg[4][2];
#pragma unroll
    for (int kk = 0; kk < 4; ++kk) {
      int kbh = wv * 4 + kk;
#pragma unroll
      for (int nt = 0; nt < 2; ++nt) {
        int n = ln & 15, q = ln >> 4;
        int row = dw * 32 + nt * 16 + n;
        int k = kbh * 32 + q * 8;
        Breg[kk][nt] = cvt8(W_hx + row * 512 + k);
      }
    }
    float bias_r[8];
#pragma unroll
    for (int it = 0; it < 8; ++it) bias_r[it] = b_hx[dw * 32 + ((it * 256 + tid) & 31)];
    int r = 0, rn = 1;
    for (int t = 0; t < SEQ; ++t) {
      if (tid < 4) pollge(&hcnt[tid * 16], (u32)(16 * t));
      __syncthreads();
      const u16* A = Abase + r * A_ELE;
      u16* dbufR = dbase + (t & 1) * D_ELE;
      short8 a[4][4];
#pragma unroll
      for (int kk = 0; kk < 4; ++kk)
#pragma unroll
        for (int mt = 0; mt < 4; ++mt)
          a[kk][mt] = ldc16(A + (((8 + wv * 4 + kk) * 4 + mt) * 64 + ln) * 8);
      f32x4 acc[2][4];
#pragma unroll
      for (int nt = 0; nt < 2; nt++)
#pragma unroll
        for (int mt = 0; mt < 4; mt++) acc[nt][mt] = (f32x4){0.f, 0.f, 0.f, 0.f};
#pragma unroll
      for (int kk = 0; kk < 4; ++kk)
#pragma unroll
        for (int nt = 0; nt < 2; nt++)
#pragma unroll
          for (int mt = 0; mt < 4; mt++)
            acc[nt][mt] = __builtin_amdgcn_mfma_f32_16x16x32_bf16(a[kk][mt], Breg[kk][nt], acc[nt][mt], 0, 0, 0);
#pragma unroll
      for (int nt = 0; nt < 2; nt++)
#pragma unroll
        for (int mt = 0; mt < 4; mt++)
          *(f32x4*)(red + ((wv * 8 + nt * 4 + mt) * 64 + ln) * 4) = acc[nt][mt];
      __syncthreads();
#pragma unroll
      for (int it = 0; it < 8; ++it) {          // 2048 outputs, 8/thread
        int item = it * 256 + tid;
        int m = item >> 5, c = item & 31;
        int mt = m >> 4, lq = ((m & 15) >> 2) * 16, reg = m & 3;
        float s = bias_r[it];
        int base = ((c >> 4) * 4 + mt) * 64 + lq + (c & 15);
#pragma unroll
        for (int w = 0; w < 4; ++w) s += red[(w * 8 * 64 + base) * 4 + reg];
        dstage[((mt * 4 + (c >> 3)) * 16 + (m & 15)) * 8 + (c & 7)] = f2bf(fast_tanh(s));
      }
      __syncthreads();
      {   // 256 x 16B coherent stores: d region = 4KB contiguous
        stc16(dbufR + (dw * 256 + tid) * 8, (const u64*)(dstage + tid * 8));
        VMCNT0();
      }
      __syncthreads();
      if (tid == 0) setflag(&dflag[dw * 16], (u32)(t + 1));
      r = rn; rn = (rn == 2) ? 0 : rn + 1;
    }
  } else {
    // ===== y WG: y = d@Wout^T + b_out; feat_{t+1} = mix*fe(y)+(1-mix)*fe(x) =====
    float* red = (float*)smem;                 // [4 wv][16 tile][64][4] = 64KB
    u16* ystage = (u16*)(smem + 65536);        // [64][80] = 10240B
    u16* fstage = (u16*)(smem + 75776);        // [64][264] = 33792B
    const int c15 = ln & 15, qq = ln >> 4;
    short8 WoR[2][4], WfR[2][4];
#pragma unroll
    for (int kk = 0; kk < 2; ++kk) {
      int koffo = (wv * 2 + kk) * 32 + qq * 8;   // W_out K-offset (K=256)
      int kofff = kk * 32 + qq * 8;              // W_fx K-offset (K=64)
#pragma unroll
      for (int nt = 0; nt < 4; ++nt) {
        WoR[kk][nt] = cvt8(W_out + (nt * 16 + c15) * 256 + koffo);
        WfR[kk][nt] = cvt8(W_fx + ((wv * 4 + nt) * 16 + c15) * 64 + kofff);
      }
    }
    float bout_r = b_out[wv * 16 + c15];
    float bfx_r[4];
#pragma unroll
    for (int nt = 0; nt < 4; ++nt) bfx_r[nt] = b_fx[(wv * 4 + nt) * 16 + c15];

    int rn = 1;
    for (int t = 0; t < SEQ; ++t) {
      // prefetch x[t+1] + msel[t+1] before the poll (plain cached loads)
      short8 xa[2][4];
      float mix = 0.f;
      if (t < SEQ - 1) {
        mix = msel[t + 1];
#pragma unroll
        for (int kb = 0; kb < 2; ++kb)
#pragma unroll
          for (int mt = 0; mt < 4; ++mt)
            xa[kb][mt] = cvt8v(x + ((t + 1) * 64 + mt * 16 + c15) * 64 + kb * 32 + qq * 8);
      }
      if (tid < 8) pollge(&dflag[tid * 16], (u32)(t + 1));
      __syncthreads();
      const u16* dbufR = dbase + (t & 1) * D_ELE;
      u16* An = Abase + rn * A_ELE;
      short8 da[2][4];
#pragma unroll
      for (int kk = 0; kk < 2; ++kk)
#pragma unroll
        for (int mt = 0; mt < 4; ++mt)
          da[kk][mt] = ldc16(dbufR + (((wv * 2 + kk) * 4 + mt) * 64 + ln) * 8);
      f32x4 acc[4][4];
#pragma unroll
      for (int nt = 0; nt < 4; nt++)
#pragma unroll
        for (int mt = 0; mt < 4; mt++) acc[nt][mt] = (f32x4){0.f, 0.f, 0.f, 0.f};
#pragma unroll
      for (int kk = 0; kk < 2; ++kk)
#pragma unroll
        for (int nt = 0; nt < 4; nt++)
#pragma unroll
          for (int mt = 0; mt < 4; mt++)
            acc[nt][mt] = __builtin_amdgcn_mfma_f32_16x16x32_bf16(da[kk][mt], WoR[kk][nt], acc[nt][mt], 0, 0, 0);
#pragma unroll
      for (int nt = 0; nt < 4; nt++)
#pragma unroll
        for (int mt = 0; mt < 4; mt++)
          *(f32x4*)(red + ((wv * 16 + nt * 4 + mt) * 64 + ln) * 4) = acc[nt][mt];
      __syncthreads();
      // wave wv finalizes output cols [wv*16, wv*16+16)
#pragma unroll
      for (int mt = 0; mt < 4; ++mt) {
        f32x4 s = (f32x4){0.f, 0.f, 0.f, 0.f};
#pragma unroll
        for (int w2 = 0; w2 < 4; ++w2)
          s += *(const f32x4*)(red + ((w2 * 16 + wv * 4 + mt) * 64 + ln) * 4);
#pragma unroll
        for (int r2 = 0; r2 < 4; ++r2) {
          float yv = s[r2] + bout_r;
          int row = mt * 16 + qq * 4 + r2;
          out[t * 4096 + row * 64 + wv * 16 + c15] = yv;   // f32 output (plain)
          ystage[row * 80 + wv * 16 + c15] = f2bf(yv);
        }
      }
      __syncthreads();
      if (t < SEQ - 1) {
        f32x4 au[4][4], tf[4][4];
#pragma unroll
        for (int nt = 0; nt < 4; nt++)
#pragma unroll
          for (int mt = 0; mt < 4; mt++) {
            au[nt][mt] = (f32x4){0.f, 0.f, 0.f, 0.f};
            tf[nt][mt] = (f32x4){0.f, 0.f, 0.f, 0.f};
          }
#pragma unroll
        for (int kb = 0; kb < 2; ++kb) {
          int koff = kb * 32 + qq * 8;
          short8 ya[4];
#pragma unroll
          for (int mt = 0; mt < 4; mt++)
            ya[mt] = *(const short8*)(ystage + (mt * 16 + c15) * 80 + koff);
#pragma unroll
          for (int nt = 0; nt < 4; nt++)
#pragma unroll
            for (int mt = 0; mt < 4; mt++) {
              au[nt][mt] = __builtin_amdgcn_mfma_f32_16x16x32_bf16(ya[mt], WfR[kb][nt], au[nt][mt], 0, 0, 0);
              tf[nt][mt] = __builtin_amdgcn_mfma_f32_16x16x32_bf16(xa[kb][mt], WfR[kb][nt], tf[nt][mt], 0, 0, 0);
            }
        }
#pragma unroll
        for (int nt = 0; nt < 4; nt++)
#pragma unroll
          for (int mt = 0; mt < 4; mt++)
#pragma unroll
            for (int r2 = 0; r2 < 4; r2++) {
              float f = mix * fast_tanh(au[nt][mt][r2] + bfx_r[nt]) +
                        (1.f - mix) * fast_tanh(tf[nt][mt][r2] + bfx_r[nt]);
              int row = mt * 16 + qq * 4 + r2;
              fstage[row * 264 + (wv * 4 + nt) * 16 + c15] = f2bf(f);
            }
        __syncthreads();
#pragma unroll
        for (int it = 0; it < 8; ++it) {       // fstage -> An feat section, coherent
          int chunk = it * 256 + tid;
          int kb = chunk >> 8, l = chunk & 63;
          int m = ((chunk >> 6) & 3) * 16 + (l & 15);
          int k = kb * 32 + (l >> 4) * 8;
          V16 v; v.s = *(const short8*)(fstage + m * 264 + k);
          stc16(An + chunk * 8, v.q);
        }
        VMCNT0();
        __syncthreads();
        if (tid == 0) setflag(fcv, (u32)(t + 1));
      }
      rn = (rn == 2) ? 0 : rn + 1;
    }
  }
}

extern "C" void kernel_launch(void* const* d_in, const int* in_sizes, int n_in,
                              void* d_out, int out_size, void* d_ws, size_t ws_size,
                              hipStream_t stream) {
  const float* x     = (const float*)d_in[0];
  const float* msel  = (const float*)d_in[1];
  const float* W_fx  = (const float*)d_in[2];
  const float* b_fx  = (const float*)d_in[3];
  const float* W_ih  = (const float*)d_in[4];
  const float* W_hh  = (const float*)d_in[5];
  const float* b_ih  = (const float*)d_in[6];
  const float* b_hh  = (const float*)d_in[7];
  const float* W_hx  = (const float*)d_in[8];
  const float* b_hx  = (const float*)d_in[9];
  const float* W_out = (const float*)d_in[10];
  const float* b_out = (const float*)d_in[11];

  uint8_t* ws = (uint8_t*)d_ws;
  u16* Abase = (u16*)ws;                    // ring of 3 x 98304 B
  u16* dbase = (u16*)(ws + 294912);         // ring of 2 x 32768 B
  u32* flags = (u32*)(ws + 360448);         // 5120 B

  prep_kernel<<<65, 256, 0, stream>>>(x, W_fx, b_fx, Abase, flags);
  rnn_kernel<<<NWG, 256, 0, stream>>>(x, msel, W_fx, b_fx, W_ih, W_hh, b_ih, b_hh,
                                      W_hx, b_hx, W_out, b_out,
                                      (float*)d_out, Abase, dbase, flags);
}